// Round 6
// baseline (209.353 us; speedup 1.0000x reference)
//
#include <hip/hip_runtime.h>
#include <hip/hip_bf16.h>

#define NROWS 32768
#define KCODES 8192
#define DDIM 128
#define TT 2048
#define ETOT 4194304  // 16*128*2048

typedef __attribute__((ext_vector_type(8))) _Float16 f16x8;
typedef __attribute__((ext_vector_type(4))) float f32x4;

// pack: clear low 13 mantissa bits, OR in payload (= 8191 - code).
// float compare then orders by (truncated value, then LOWER code first).
__device__ __forceinline__ float pk(float v, int payload) {
    return __int_as_float((__float_as_int(v) & 0xFFFFE000) | payload);
}

// ---------------------------------------------------------------------------
// k1: normalize codebook rows, fp32 -> fp16, store in MFMA A-fragment order
//     per 128-code tile (32KB each): 8 cg-groups of 16 codes x 4 k-slices.
// code w: tile=w>>7, cg=(w>>4)&7, c=w&15 ; dim d: ks=d>>5, kq=(d>>3)&3, dr=d&7
// elem off = tile*16384 + ((ks*8+cg)*64 + kq*16 + c)*8 + dr
// ---------------------------------------------------------------------------
__global__ void k_en_prep(const float* __restrict__ cb,
                          _Float16* __restrict__ eh) {
    int w = (blockIdx.x * blockDim.x + threadIdx.x) >> 6;  // code id
    int l = threadIdx.x & 63;
    if (w >= KCODES) return;
    const float* row = cb + (long)w * DDIM;
    float v0 = row[l], v1 = row[l + 64];
    float ss = v0 * v0 + v1 * v1;
#pragma unroll
    for (int s = 1; s < 64; s <<= 1) ss += __shfl_xor(ss, s, 64);
    float inv = 1.0f / fmaxf(sqrtf(ss), 1e-12f);
    int tile = w >> 7, cg = (w >> 4) & 7, c = w & 15;
#pragma unroll
    for (int e = 0; e < 2; e++) {
        int d = l + e * 64;
        float v = (e ? v1 : v0) * inv;
        int ks = d >> 5, kq = (d >> 3) & 3, dr = d & 7;
        long off = (long)tile * 16384 + (((ks * 8 + cg) * 64) + kq * 16 + c) * 8 + dr;
        eh[off] = (_Float16)v;
    }
}

// ---------------------------------------------------------------------------
// k2: transpose inputs [B,D,T] -> xh [N=B*T, D] row-major fp16.
// ---------------------------------------------------------------------------
__global__ void k_x_prep(const float* __restrict__ in,
                         _Float16* __restrict__ xh) {
    __shared__ float tb[64][65];
    int bid = blockIdx.x;
    int tt0 = (bid & 31) * 64;
    int dd0 = ((bid >> 5) & 1) * 64;
    int b = bid >> 6;
    const float* base = in + (long)b * DDIM * TT;
    int tl = threadIdx.x & 63;
    int dg = threadIdx.x >> 6;
#pragma unroll
    for (int i = 0; i < 16; i++) {
        int dd = dg + i * 4;
        tb[dd][tl] = base[(long)(dd0 + dd) * TT + tt0 + tl];
    }
    __syncthreads();
    int dl = threadIdx.x & 63;
    int tg = threadIdx.x >> 6;
#pragma unroll
    for (int i = 0; i < 16; i++) {
        int t = tg + i * 4;
        long n = (long)b * TT + tt0 + t;
        xh[n * DDIM + dd0 + dl] = (_Float16)tb[dl][t];
    }
}

// ---------------------------------------------------------------------------
// k3 v6: fp16 GEMM + packed selection, no LDS staging, REGISTER-DOUBLE-
// BUFFERED A-tile (ping/pong pa/pb, explicit 2-phase loop) so the next
// tile's 4 dwordx4 L2 loads fly under the current tile's MFMA+VALU.
// 512 blocks x 512 thr; 8 waves = 8 cg (16 codes each); block = 64 xrows.
// Tile = 128 codes, 64 tiles. Selection: pk -> pure min/max networks.
// Per lane: quad-top-2 -> top-3 stream + quad-2nd top-1 stream; epilogue
// merges 128 entries/row -> global top-4 -> exact fp64 refine (k4).
// ---------------------------------------------------------------------------
__device__ __forceinline__ void load_a(f16x8 (&a)[4], const f16x8* ep) {
    a[0] = ep[0];
    a[1] = ep[512];
    a[2] = ep[1024];
    a[3] = ep[1536];
}

__device__ __forceinline__ void tile_step(
    const f16x8 (&ah)[4], const f16x8 (&bx)[4][4], int P,
    float (&t1)[4], float (&t2)[4], float (&t3)[4], float (&u1)[4]) {
    f32x4 acc[4];
#pragma unroll
    for (int nf = 0; nf < 4; nf++) acc[nf] = (f32x4){0.f, 0.f, 0.f, 0.f};
#pragma unroll
    for (int nf = 0; nf < 4; nf++) {
        acc[nf] = __builtin_amdgcn_mfma_f32_16x16x32_f16(ah[0], bx[nf][0], acc[nf], 0, 0, 0);
        acc[nf] = __builtin_amdgcn_mfma_f32_16x16x32_f16(ah[1], bx[nf][1], acc[nf], 0, 0, 0);
        acc[nf] = __builtin_amdgcn_mfma_f32_16x16x32_f16(ah[2], bx[nf][2], acc[nf], 0, 0, 0);
        acc[nf] = __builtin_amdgcn_mfma_f32_16x16x32_f16(ah[3], bx[nf][3], acc[nf], 0, 0, 0);
    }
#pragma unroll
    for (int nf = 0; nf < 4; nf++) {
        f32x4 a = acc[nf];
        float s0 = pk(a[0], P),     s1 = pk(a[1], P - 1);
        float s2 = pk(a[2], P - 2), s3 = pk(a[3], P - 3);
        float h01 = fmaxf(s0, s1), l01 = fminf(s0, s1);
        float h23 = fmaxf(s2, s3), l23 = fminf(s2, s3);
        float m1 = fmaxf(h01, h23);                          // quad max
        float m2 = fmaxf(fminf(h01, h23), fmaxf(l01, l23));  // quad 2nd
        float n1 = fminf(t1[nf], m1); t1[nf] = fmaxf(t1[nf], m1);
        float n2 = fminf(t2[nf], n1); t2[nf] = fmaxf(t2[nf], n1);
        t3[nf] = fmaxf(t3[nf], n2);
        u1[nf] = fmaxf(u1[nf], m2);
    }
}

__launch_bounds__(512, 4)
__global__ void k_main(const _Float16* __restrict__ xh,
                       const _Float16* __restrict__ eh,
                       int* __restrict__ cand) {
    __shared__ float mrg[128 * 65];  // epilogue merge area (33.3 KB)
    const int tid = threadIdx.x;
    const int l = tid & 63;
    const int cg = tid >> 6;         // 0..7 : 16-code group within tile
    const int col = l & 15, kq = l >> 4;
    const long rbase = (long)blockIdx.x * 64;

    // B-operand x-fragments in registers (loaded once): 4 nf x 4 ks
    f16x8 bx[4][4];
#pragma unroll
    for (int nf = 0; nf < 4; nf++) {
        long n = rbase + nf * 16 + col;
#pragma unroll
        for (int ks = 0; ks < 4; ks++)
            bx[nf][ks] = *(const f16x8*)(xh + n * DDIM + ks * 32 + kq * 8);
    }

    const float NEG = __int_as_float(0xFF800000);  // -inf (payload bits 0)
    float t1[4], t2[4], t3[4], u1[4];
#pragma unroll
    for (int i = 0; i < 4; i++) { t1[i] = t2[i] = t3[i] = u1[i] = NEG; }

    int P = 8191 - (cg * 16 + kq * 4);   // payload base; code = 8191 - payload

    const f16x8* ep = (const f16x8*)eh + cg * 64 + l;
    f16x8 pa[4], pb[4];
    load_a(pa, ep); ep += 2048;

    for (int t = 0; t < 64; t += 2) {
        load_a(pb, ep); ep += 2048;                     // prefetch tile t+1
        tile_step(pa, bx, P, t1, t2, t3, u1); P -= 128; // compute tile t
        if (t + 2 < 64) { load_a(pa, ep); ep += 2048; } // prefetch tile t+2
        tile_step(pb, bx, P, t1, t2, t3, u1); P -= 128; // compute tile t+1
    }

    // epilogue: 128 entries per row
    const int e0 = cg * 16 + kq * 4;
#pragma unroll
    for (int nf = 0; nf < 4; nf++) {
        int row = nf * 16 + col;
        mrg[(e0 + 0) * 65 + row] = t1[nf];
        mrg[(e0 + 1) * 65 + row] = t2[nf];
        mrg[(e0 + 2) * 65 + row] = t3[nf];
        mrg[(e0 + 3) * 65 + row] = u1[nf];
    }
    __syncthreads();
    if (tid < 64) {
        float s1 = NEG, s2 = NEG, s3 = NEG, s4 = NEG;
#pragma unroll 8
        for (int e = 0; e < 128; e++) {
            float v = mrg[e * 65 + tid];
            float a1 = fminf(s1, v); s1 = fmaxf(s1, v);
            float a2 = fminf(s2, a1); s2 = fmaxf(s2, a1);
            float a3 = fminf(s3, a2); s3 = fmaxf(s3, a2);
            s4 = fmaxf(s4, a3);
        }
        long n = rbase + tid;
        cand[n * 4 + 0] = 8191 - (__float_as_int(s1) & 0x1FFF);
        cand[n * 4 + 1] = 8191 - (__float_as_int(s2) & 0x1FFF);
        cand[n * 4 + 2] = 8191 - (__float_as_int(s3) & 0x1FFF);
        cand[n * 4 + 3] = 8191 - (__float_as_int(s4) & 0x1FFF);
    }
}

// ---------------------------------------------------------------------------
// k4 v2: fp64 exact re-evaluation, THREAD-PER-ROW (coalesced x reads:
// consecutive threads = consecutive t). cb rows streamed as float4 from L2.
// ---------------------------------------------------------------------------
__global__ void k_refine(const float* __restrict__ in, const float* __restrict__ cb,
                         const int* __restrict__ cand, int* __restrict__ idx_out,
                         float* __restrict__ idx_f) {
    int n = blockIdx.x * blockDim.x + threadIdx.x;
    if (n >= NROWS) return;
    int b = n >> 11, t = n & 2047;
    const float* xb = in + (long)b * DDIM * TT + t;
    int c[4];
#pragma unroll
    for (int k = 0; k < 4; k++) c[k] = cand[n * 4 + k];
    const float4* e0 = (const float4*)(cb + (long)c[0] * DDIM);
    const float4* e1 = (const float4*)(cb + (long)c[1] * DDIM);
    const float4* e2 = (const float4*)(cb + (long)c[2] * DDIM);
    const float4* e3 = (const float4*)(cb + (long)c[3] * DDIM);
    double dot[4] = {0, 0, 0, 0}, nrm[4] = {0, 0, 0, 0};
    for (int d4 = 0; d4 < 32; d4++) {
        float4 q0 = e0[d4], q1 = e1[d4], q2 = e2[d4], q3 = e3[d4];
#pragma unroll
        for (int j = 0; j < 4; j++) {
            double xd = (double)xb[(long)(d4 * 4 + j) * TT];
            double f0 = (double)((const float*)&q0)[j];
            double f1 = (double)((const float*)&q1)[j];
            double f2 = (double)((const float*)&q2)[j];
            double f3 = (double)((const float*)&q3)[j];
            dot[0] += xd * f0; nrm[0] += f0 * f0;
            dot[1] += xd * f1; nrm[1] += f1 * f1;
            dot[2] += xd * f2; nrm[2] += f2 * f2;
            dot[3] += xd * f3; nrm[3] += f3 * f3;
        }
    }
    double best = -1e300;
    int bi = 0x7fffffff;
#pragma unroll
    for (int k = 0; k < 4; k++) {
        double sv = dot[k] / fmax(sqrt(nrm[k]), 1e-12);
        if (sv > best || (sv == best && c[k] < bi)) { best = sv; bi = c[k]; }
    }
    idx_out[n] = bi;
    idx_f[n] = (float)bi;
}

// ---------------------------------------------------------------------------
// k5: out = x + (q - x) in [B,D,T] order + fp64 partial sums of (q-x)^2.
// ---------------------------------------------------------------------------
__global__ void k_out_loss(const float* __restrict__ in, const float* __restrict__ cb,
                           const int* __restrict__ idx, float* __restrict__ out,
                           double* __restrict__ part) {
    __shared__ double sd[256];
    double acc = 0.0;
    for (long e = (long)blockIdx.x * blockDim.x + threadIdx.x; e < ETOT;
         e += (long)gridDim.x * blockDim.x) {
        long t = e & 2047;
        long d = (e >> 11) & 127;
        long b = e >> 18;
        float xv = in[e];
        int n = (int)((b << 11) | t);
        float qv = cb[(long)idx[n] * DDIM + d];
        float diff = qv - xv;
        out[e] = xv + diff;
        acc += (double)diff * (double)diff;
    }
    sd[threadIdx.x] = acc;
    __syncthreads();
    for (int s = 128; s > 0; s >>= 1) {
        if (threadIdx.x < s) sd[threadIdx.x] += sd[threadIdx.x + s];
        __syncthreads();
    }
    if (threadIdx.x == 0) part[blockIdx.x] = sd[0];
}

__global__ void k_loss_final(const double* __restrict__ part, int np,
                             float* __restrict__ loss) {
    __shared__ double sd[256];
    double a = 0.0;
    for (int i = threadIdx.x; i < np; i += 256) a += part[i];
    sd[threadIdx.x] = a;
    __syncthreads();
    for (int s = 128; s > 0; s >>= 1) {
        if (threadIdx.x < s) sd[threadIdx.x] += sd[threadIdx.x + s];
        __syncthreads();
    }
    if (threadIdx.x == 0) {
        float m = (float)(sd[0] / (double)ETOT);
        loss[0] = m + 0.02f * m;
    }
}

// ---------------------------------------------------------------------------
extern "C" void kernel_launch(void* const* d_in, const int* in_sizes, int n_in,
                              void* d_out, int out_size, void* d_ws, size_t ws_size,
                              hipStream_t stream) {
    const float* inputs = (const float*)d_in[0];   // [16,128,2048] fp32
    const float* cb     = (const float*)d_in[1];   // [8192,128]    fp32
    float* outf = (float*)d_out;                   // [loss | out(B,D,T) | idx]

    char* ws = (char*)d_ws;
    _Float16* xh = (_Float16*)ws; ws += (long)NROWS * DDIM * 2;
    _Float16* eh = (_Float16*)ws; ws += (long)KCODES * DDIM * 2;
    int* cand    = (int*)ws;      ws += (long)NROWS * 4 * 4;
    int* idx     = (int*)ws;      ws += (long)NROWS * 4;
    double* part = (double*)ws;   ws += 2048 * 8;

    k_en_prep<<<dim3(2048), dim3(256), 0, stream>>>(cb, eh);
    k_x_prep<<<dim3(1024), dim3(256), 0, stream>>>(inputs, xh);
    k_main<<<dim3(512), dim3(512), 0, stream>>>(xh, eh, cand);
    k_refine<<<dim3(128), dim3(256), 0, stream>>>(inputs, cb, cand, idx,
                                                  outf + 1 + (long)ETOT);
    k_out_loss<<<dim3(2048), dim3(256), 0, stream>>>(inputs, cb, idx, outf + 1, part);
    k_loss_final<<<dim3(1), dim3(256), 0, stream>>>(part, 2048, outf);
}

// Round 7
// 179.112 us; speedup vs baseline: 1.1688x; 1.1688x over previous
//
#include <hip/hip_runtime.h>
#include <hip/hip_bf16.h>

#define NROWS 32768
#define KCODES 8192
#define DDIM 128
#define TT 2048
#define ETOT 4194304  // 16*128*2048

typedef __attribute__((ext_vector_type(8))) _Float16 f16x8;
typedef __attribute__((ext_vector_type(4))) float f32x4;

// pack: clear low 13 mantissa bits, OR in payload (= 8191 - code).
// float compare then orders by (truncated value, then LOWER code first).
__device__ __forceinline__ float pk(float v, int payload) {
    return __int_as_float((__float_as_int(v) & 0xFFFFE000) | payload);
}

// ---------------------------------------------------------------------------
// k1: normalize codebook rows, fp32 -> fp16, store in MFMA A-fragment order
//     per 128-code tile (32KB each): 8 cg-groups of 16 codes x 4 k-slices.
// code w: tile=w>>7, cg=(w>>4)&7, c=w&15 ; dim d: ks=d>>5, kq=(d>>3)&3, dr=d&7
// elem off = tile*16384 + ((ks*8+cg)*64 + kq*16 + c)*8 + dr
// ---------------------------------------------------------------------------
__global__ void k_en_prep(const float* __restrict__ cb,
                          _Float16* __restrict__ eh) {
    int w = (blockIdx.x * blockDim.x + threadIdx.x) >> 6;  // code id
    int l = threadIdx.x & 63;
    if (w >= KCODES) return;
    const float* row = cb + (long)w * DDIM;
    float v0 = row[l], v1 = row[l + 64];
    float ss = v0 * v0 + v1 * v1;
#pragma unroll
    for (int s = 1; s < 64; s <<= 1) ss += __shfl_xor(ss, s, 64);
    float inv = 1.0f / fmaxf(sqrtf(ss), 1e-12f);
    int tile = w >> 7, cg = (w >> 4) & 7, c = w & 15;
#pragma unroll
    for (int e = 0; e < 2; e++) {
        int d = l + e * 64;
        float v = (e ? v1 : v0) * inv;
        int ks = d >> 5, kq = (d >> 3) & 3, dr = d & 7;
        long off = (long)tile * 16384 + (((ks * 8 + cg) * 64) + kq * 16 + c) * 8 + dr;
        eh[off] = (_Float16)v;
    }
}

// ---------------------------------------------------------------------------
// k2: transpose inputs [B,D,T] -> xh [N=B*T, D] row-major fp16.
// ---------------------------------------------------------------------------
__global__ void k_x_prep(const float* __restrict__ in,
                         _Float16* __restrict__ xh) {
    __shared__ float tb[64][65];
    int bid = blockIdx.x;
    int tt0 = (bid & 31) * 64;
    int dd0 = ((bid >> 5) & 1) * 64;
    int b = bid >> 6;
    const float* base = in + (long)b * DDIM * TT;
    int tl = threadIdx.x & 63;
    int dg = threadIdx.x >> 6;
#pragma unroll
    for (int i = 0; i < 16; i++) {
        int dd = dg + i * 4;
        tb[dd][tl] = base[(long)(dd0 + dd) * TT + tt0 + tl];
    }
    __syncthreads();
    int dl = threadIdx.x & 63;
    int tg = threadIdx.x >> 6;
#pragma unroll
    for (int i = 0; i < 16; i++) {
        int t = tg + i * 4;
        long n = (long)b * TT + tt0 + t;
        xh[n * DDIM + dd0 + dl] = (_Float16)tb[dl][t];
    }
}

// ---------------------------------------------------------------------------
// k3 v7: fp16 GEMM + packed selection, no LDS staging, SMALL working set so
// x-fragments stay register-resident (round-5/6 kept re-loading bx: 64 VGPRs
// reported vs 64 needed for bx alone).
// 1024 blocks x 512 thr; block = 32 xrows; 8 waves = 8 cg (16 codes each).
// Tile = 128 codes, 64 tiles. bx[2][4]=32 VGPRs. Round-5 loop shape
// (compiler-scheduled, unroll 2); manual ping/pong removed (round-6 lesson).
// Selection: pk -> pure min/max networks; per lane quad-top-2 -> top-3 +
// quad-2nd top-1; epilogue merges 128 entries/row -> global top-4 -> k4.
// ---------------------------------------------------------------------------
__launch_bounds__(512, 4)
__global__ void k_main(const _Float16* __restrict__ xh,
                       const _Float16* __restrict__ eh,
                       int* __restrict__ cand) {
    __shared__ float mrg[128 * 33];  // epilogue merge area (16.9 KB)
    const int tid = threadIdx.x;
    const int l = tid & 63;
    const int cg = tid >> 6;         // 0..7 : 16-code group within tile
    const int col = l & 15, kq = l >> 4;
    const long rbase = (long)blockIdx.x * 32;

    // B-operand x-fragments in registers (loaded once): 2 nf x 4 ks = 32 VGPR
    f16x8 bx[2][4];
#pragma unroll
    for (int nf = 0; nf < 2; nf++) {
        long n = rbase + nf * 16 + col;
#pragma unroll
        for (int ks = 0; ks < 4; ks++)
            bx[nf][ks] = *(const f16x8*)(xh + n * DDIM + ks * 32 + kq * 8);
    }

    const float NEG = __int_as_float(0xFF800000);  // -inf (payload bits 0)
    float t1[2], t2[2], t3[2], u1[2];
#pragma unroll
    for (int i = 0; i < 2; i++) { t1[i] = t2[i] = t3[i] = u1[i] = NEG; }

    int P = 8191 - (cg * 16 + kq * 4);   // payload base; code = 8191 - payload

    const f16x8* ep = (const f16x8*)eh + cg * 64 + l;

#pragma unroll 2
    for (int t = 0; t < 64; ++t) {
        f16x8 ah0 = ep[0];
        f16x8 ah1 = ep[512];
        f16x8 ah2 = ep[1024];
        f16x8 ah3 = ep[1536];
        ep += 2048;

        f32x4 acc[2];
        acc[0] = (f32x4){0.f, 0.f, 0.f, 0.f};
        acc[1] = (f32x4){0.f, 0.f, 0.f, 0.f};
#pragma unroll
        for (int nf = 0; nf < 2; nf++) {
            acc[nf] = __builtin_amdgcn_mfma_f32_16x16x32_f16(ah0, bx[nf][0], acc[nf], 0, 0, 0);
            acc[nf] = __builtin_amdgcn_mfma_f32_16x16x32_f16(ah1, bx[nf][1], acc[nf], 0, 0, 0);
            acc[nf] = __builtin_amdgcn_mfma_f32_16x16x32_f16(ah2, bx[nf][2], acc[nf], 0, 0, 0);
            acc[nf] = __builtin_amdgcn_mfma_f32_16x16x32_f16(ah3, bx[nf][3], acc[nf], 0, 0, 0);
        }

        // index-free selection on packed floats
#pragma unroll
        for (int nf = 0; nf < 2; nf++) {
            f32x4 a = acc[nf];
            float s0 = pk(a[0], P),     s1 = pk(a[1], P - 1);
            float s2 = pk(a[2], P - 2), s3 = pk(a[3], P - 3);
            float h01 = fmaxf(s0, s1), l01 = fminf(s0, s1);
            float h23 = fmaxf(s2, s3), l23 = fminf(s2, s3);
            float m1 = fmaxf(h01, h23);                          // quad max
            float m2 = fmaxf(fminf(h01, h23), fmaxf(l01, l23));  // quad 2nd
            float n1 = fminf(t1[nf], m1); t1[nf] = fmaxf(t1[nf], m1);
            float n2 = fminf(t2[nf], n1); t2[nf] = fmaxf(t2[nf], n1);
            t3[nf] = fmaxf(t3[nf], n2);
            u1[nf] = fmaxf(u1[nf], m2);
        }
        P -= 128;
    }

    // epilogue: 128 packed entries per row -> LDS
    const int e0 = cg * 16 + kq * 4;
#pragma unroll
    for (int nf = 0; nf < 2; nf++) {
        int row = nf * 16 + col;
        mrg[(e0 + 0) * 33 + row] = t1[nf];
        mrg[(e0 + 1) * 33 + row] = t2[nf];
        mrg[(e0 + 2) * 33 + row] = t3[nf];
        mrg[(e0 + 3) * 33 + row] = u1[nf];
    }
    __syncthreads();
    if (tid < 32) {
        float s1 = NEG, s2 = NEG, s3 = NEG, s4 = NEG;
#pragma unroll 8
        for (int e = 0; e < 128; e++) {
            float v = mrg[e * 33 + tid];
            float a1 = fminf(s1, v); s1 = fmaxf(s1, v);
            float a2 = fminf(s2, a1); s2 = fmaxf(s2, a1);
            float a3 = fminf(s3, a2); s3 = fmaxf(s3, a2);
            s4 = fmaxf(s4, a3);
        }
        long n = rbase + tid;
        cand[n * 4 + 0] = 8191 - (__float_as_int(s1) & 0x1FFF);
        cand[n * 4 + 1] = 8191 - (__float_as_int(s2) & 0x1FFF);
        cand[n * 4 + 2] = 8191 - (__float_as_int(s3) & 0x1FFF);
        cand[n * 4 + 3] = 8191 - (__float_as_int(s4) & 0x1FFF);
    }
}

// ---------------------------------------------------------------------------
// k4 v2: fp64 exact re-evaluation, thread-per-row (coalesced x reads).
// ---------------------------------------------------------------------------
__global__ void k_refine(const float* __restrict__ in, const float* __restrict__ cb,
                         const int* __restrict__ cand, int* __restrict__ idx_out,
                         float* __restrict__ idx_f) {
    int n = blockIdx.x * blockDim.x + threadIdx.x;
    if (n >= NROWS) return;
    int b = n >> 11, t = n & 2047;
    const float* xb = in + (long)b * DDIM * TT + t;
    int c[4];
#pragma unroll
    for (int k = 0; k < 4; k++) c[k] = cand[n * 4 + k];
    const float4* e0 = (const float4*)(cb + (long)c[0] * DDIM);
    const float4* e1 = (const float4*)(cb + (long)c[1] * DDIM);
    const float4* e2 = (const float4*)(cb + (long)c[2] * DDIM);
    const float4* e3 = (const float4*)(cb + (long)c[3] * DDIM);
    double dot[4] = {0, 0, 0, 0}, nrm[4] = {0, 0, 0, 0};
    for (int d4 = 0; d4 < 32; d4++) {
        float4 q0 = e0[d4], q1 = e1[d4], q2 = e2[d4], q3 = e3[d4];
#pragma unroll
        for (int j = 0; j < 4; j++) {
            double xd = (double)xb[(long)(d4 * 4 + j) * TT];
            double f0 = (double)((const float*)&q0)[j];
            double f1 = (double)((const float*)&q1)[j];
            double f2 = (double)((const float*)&q2)[j];
            double f3 = (double)((const float*)&q3)[j];
            dot[0] += xd * f0; nrm[0] += f0 * f0;
            dot[1] += xd * f1; nrm[1] += f1 * f1;
            dot[2] += xd * f2; nrm[2] += f2 * f2;
            dot[3] += xd * f3; nrm[3] += f3 * f3;
        }
    }
    double best = -1e300;
    int bi = 0x7fffffff;
#pragma unroll
    for (int k = 0; k < 4; k++) {
        double sv = dot[k] / fmax(sqrt(nrm[k]), 1e-12);
        if (sv > best || (sv == best && c[k] < bi)) { best = sv; bi = c[k]; }
    }
    idx_out[n] = bi;
    idx_f[n] = (float)bi;
}

// ---------------------------------------------------------------------------
// k5: out = x + (q - x) in [B,D,T] order + fp64 partial sums of (q-x)^2.
// ---------------------------------------------------------------------------
__global__ void k_out_loss(const float* __restrict__ in, const float* __restrict__ cb,
                           const int* __restrict__ idx, float* __restrict__ out,
                           double* __restrict__ part) {
    __shared__ double sd[256];
    double acc = 0.0;
    for (long e = (long)blockIdx.x * blockDim.x + threadIdx.x; e < ETOT;
         e += (long)gridDim.x * blockDim.x) {
        long t = e & 2047;
        long d = (e >> 11) & 127;
        long b = e >> 18;
        float xv = in[e];
        int n = (int)((b << 11) | t);
        float qv = cb[(long)idx[n] * DDIM + d];
        float diff = qv - xv;
        out[e] = xv + diff;
        acc += (double)diff * (double)diff;
    }
    sd[threadIdx.x] = acc;
    __syncthreads();
    for (int s = 128; s > 0; s >>= 1) {
        if (threadIdx.x < s) sd[threadIdx.x] += sd[threadIdx.x + s];
        __syncthreads();
    }
    if (threadIdx.x == 0) part[blockIdx.x] = sd[0];
}

__global__ void k_loss_final(const double* __restrict__ part, int np,
                             float* __restrict__ loss) {
    __shared__ double sd[256];
    double a = 0.0;
    for (int i = threadIdx.x; i < np; i += 256) a += part[i];
    sd[threadIdx.x] = a;
    __syncthreads();
    for (int s = 128; s > 0; s >>= 1) {
        if (threadIdx.x < s) sd[threadIdx.x] += sd[threadIdx.x + s];
        __syncthreads();
    }
    if (threadIdx.x == 0) {
        float m = (float)(sd[0] / (double)ETOT);
        loss[0] = m + 0.02f * m;
    }
}

// ---------------------------------------------------------------------------
extern "C" void kernel_launch(void* const* d_in, const int* in_sizes, int n_in,
                              void* d_out, int out_size, void* d_ws, size_t ws_size,
                              hipStream_t stream) {
    const float* inputs = (const float*)d_in[0];   // [16,128,2048] fp32
    const float* cb     = (const float*)d_in[1];   // [8192,128]    fp32
    float* outf = (float*)d_out;                   // [loss | out(B,D,T) | idx]

    char* ws = (char*)d_ws;
    _Float16* xh = (_Float16*)ws; ws += (long)NROWS * DDIM * 2;
    _Float16* eh = (_Float16*)ws; ws += (long)KCODES * DDIM * 2;
    int* cand    = (int*)ws;      ws += (long)NROWS * 4 * 4;
    int* idx     = (int*)ws;      ws += (long)NROWS * 4;
    double* part = (double*)ws;   ws += 2048 * 8;

    k_en_prep<<<dim3(2048), dim3(256), 0, stream>>>(cb, eh);
    k_x_prep<<<dim3(1024), dim3(256), 0, stream>>>(inputs, xh);
    k_main<<<dim3(1024), dim3(512), 0, stream>>>(xh, eh, cand);
    k_refine<<<dim3(128), dim3(256), 0, stream>>>(inputs, cb, cand, idx,
                                                  outf + 1 + (long)ETOT);
    k_out_loss<<<dim3(2048), dim3(256), 0, stream>>>(inputs, cb, idx, outf + 1, part);
    k_loss_final<<<dim3(1), dim3(256), 0, stream>>>(part, 2048, outf);
}

// Round 8
// 169.996 us; speedup vs baseline: 1.2315x; 1.0536x over previous
//
#include <hip/hip_runtime.h>
#include <hip/hip_bf16.h>

#define NROWS 32768
#define KCODES 8192
#define DDIM 128
#define TT 2048
#define ETOT 4194304  // 16*128*2048

typedef __attribute__((ext_vector_type(8))) _Float16 f16x8;
typedef __attribute__((ext_vector_type(4))) float f32x4;

// pack: clear low 13 mantissa bits, OR in payload (= 8191 - code).
// float compare then orders by (truncated value, then LOWER code first).
__device__ __forceinline__ float pk(float v, int payload) {
    return __int_as_float((__float_as_int(v) & 0xFFFFE000) | payload);
}

__device__ __forceinline__ void async16(char* lds_uniform, const char* g_perlane) {
    __builtin_amdgcn_global_load_lds(
        (const __attribute__((address_space(1))) unsigned int*)g_perlane,
        (__attribute__((address_space(3))) unsigned int*)lds_uniform,
        16, 0, 0);
}

// ---------------------------------------------------------------------------
// k1: normalize codebook rows, fp32 -> fp16, store in MFMA A-fragment order
//     per 16-code tile (4KB each), so k_main's LDS staging is linear and
//     ds_read_b128 is conflict-free.
// code w: tile16=w>>4, c=w&15 ; dim d: ks=d>>5, kq=(d>>3)&3, dr=d&7
// elem off = tile16*2048 + ks*512 + (kq*16 + c)*8 + dr
// ---------------------------------------------------------------------------
__global__ void k_en_prep(const float* __restrict__ cb,
                          _Float16* __restrict__ eh) {
    int w = (blockIdx.x * blockDim.x + threadIdx.x) >> 6;  // code id
    int l = threadIdx.x & 63;
    if (w >= KCODES) return;
    const float* row = cb + (long)w * DDIM;
    float v0 = row[l], v1 = row[l + 64];
    float ss = v0 * v0 + v1 * v1;
#pragma unroll
    for (int s = 1; s < 64; s <<= 1) ss += __shfl_xor(ss, s, 64);
    float inv = 1.0f / fmaxf(sqrtf(ss), 1e-12f);
    int tile = w >> 4, c = w & 15;
#pragma unroll
    for (int e = 0; e < 2; e++) {
        int d = l + e * 64;
        float v = (e ? v1 : v0) * inv;
        int ks = d >> 5, kq = (d >> 3) & 3, dr = d & 7;
        long off = (long)tile * 2048 + ks * 512 + (kq * 16 + c) * 8 + dr;
        eh[off] = (_Float16)v;
    }
}

// ---------------------------------------------------------------------------
// k2: transpose inputs [B,D,T] -> xh [N=B*T, D] row-major fp16.
// ---------------------------------------------------------------------------
__global__ void k_x_prep(const float* __restrict__ in,
                         _Float16* __restrict__ xh) {
    __shared__ float tb[64][65];
    int bid = blockIdx.x;
    int tt0 = (bid & 31) * 64;
    int dd0 = ((bid >> 5) & 1) * 64;
    int b = bid >> 6;
    const float* base = in + (long)b * DDIM * TT;
    int tl = threadIdx.x & 63;
    int dg = threadIdx.x >> 6;
#pragma unroll
    for (int i = 0; i < 16; i++) {
        int dd = dg + i * 4;
        tb[dd][tl] = base[(long)(dd0 + dd) * TT + tt0 + tl];
    }
    __syncthreads();
    int dl = threadIdx.x & 63;
    int tg = threadIdx.x >> 6;
#pragma unroll
    for (int i = 0; i < 16; i++) {
        int t = tg + i * 4;
        long n = (long)b * TT + tt0 + t;
        xh[n * DDIM + dd0 + dl] = (_Float16)tb[dl][t];
    }
}

// ---------------------------------------------------------------------------
// k3 v8: fp16 GEMM + packed selection with BARRIER-FREE private LDS staging.
// 512 blocks x 512 thr; block = 64 xrows; 8 waves, each OWNS a private
// 1024-code stream (64 tiles x 16 codes) double-buffered in its own 8KB LDS
// slice via global_load_lds. Per tile: stage t+1 (4 async16) -> counted
// s_waitcnt vmcnt(4) -> 4 ds_read_b128 -> 16 MFMA (setprio-wrapped) -> quad
// selection. NO s_barrier in the main loop: waves free-run, L2 latency rides
// the staging queue (~2000 cyc ahead), eh L2 traffic = 1 GB (block-shared).
// Selection: pk -> pure min/max; per lane quad-top-2 -> top-3 + 2nd-stream
// top-1; epilogue merges 128 entries/row -> global top-4 -> fp64 refine (k4).
// ---------------------------------------------------------------------------
__global__ __launch_bounds__(512) void k_main(const _Float16* __restrict__ xh,
                                              const _Float16* __restrict__ eh,
                                              int* __restrict__ cand) {
    extern __shared__ char lds[];
    const int tid = threadIdx.x;
    const int l = tid & 63;
    const int w = tid >> 6;          // 0..7 : wave id, owns codes [w*1024, w*1024+1024)
    const int col = l & 15, kq = l >> 4;
    const long rbase = (long)blockIdx.x * 64;

    // B-operand x-fragments in registers/AGPRs (loaded once): 4 nf x 4 ks
    f16x8 bx[4][4];
#pragma unroll
    for (int nf = 0; nf < 4; nf++) {
        long n = rbase + nf * 16 + col;
#pragma unroll
        for (int ks = 0; ks < 4; ks++)
            bx[nf][ks] = *(const f16x8*)(xh + n * DDIM + ks * 32 + kq * 8);
    }

    const float NEG = __int_as_float(0xFF800000);  // -inf (payload bits 0)
    float t1[4], t2[4], t3[4], u1[4];
#pragma unroll
    for (int i = 0; i < 4; i++) { t1[i] = t2[i] = t3[i] = u1[i] = NEG; }

    int P = 8191 - (w * 1024 + kq * 4);  // payload; code = 8191 - payload

    const char* gsrc = (const char*)eh + (long)w * 64 * 4096 + l * 16;
    char* lbase = lds + w * 8192;        // private 2 x 4KB double buffer

    // prologue: stage tile 0 into buf 0 (LDS dest is wave-uniform; HW adds lane*16)
#pragma unroll
    for (int ks = 0; ks < 4; ks++)
        async16(lbase + ks * 1024, gsrc + ks * 1024);

#pragma unroll 2
    for (int t = 0; t < 64; ++t) {
        if (t < 63) {
            const char* gs = gsrc + (t + 1) * 4096;
            char* nb = lbase + ((t + 1) & 1) * 4096;
#pragma unroll
            for (int ks = 0; ks < 4; ks++)
                async16(nb + ks * 1024, gs + ks * 1024);
            asm volatile("s_waitcnt vmcnt(4)" ::: "memory");  // tile t landed
        } else {
            asm volatile("s_waitcnt vmcnt(0)" ::: "memory");  // final drain
        }

        const char* buf = lbase + (t & 1) * 4096;
        f16x8 ah[4];
#pragma unroll
        for (int ks = 0; ks < 4; ks++)
            ah[ks] = *(const f16x8*)(buf + ks * 1024 + l * 16);

        f32x4 acc[4];
#pragma unroll
        for (int nf = 0; nf < 4; nf++) acc[nf] = (f32x4){0.f, 0.f, 0.f, 0.f};
        __builtin_amdgcn_s_setprio(1);
#pragma unroll
        for (int nf = 0; nf < 4; nf++) {
            acc[nf] = __builtin_amdgcn_mfma_f32_16x16x32_f16(ah[0], bx[nf][0], acc[nf], 0, 0, 0);
            acc[nf] = __builtin_amdgcn_mfma_f32_16x16x32_f16(ah[1], bx[nf][1], acc[nf], 0, 0, 0);
            acc[nf] = __builtin_amdgcn_mfma_f32_16x16x32_f16(ah[2], bx[nf][2], acc[nf], 0, 0, 0);
            acc[nf] = __builtin_amdgcn_mfma_f32_16x16x32_f16(ah[3], bx[nf][3], acc[nf], 0, 0, 0);
        }
        __builtin_amdgcn_s_setprio(0);

        // index-free selection on packed floats (code = w*1024 + t*16 + kq*4 + j)
#pragma unroll
        for (int nf = 0; nf < 4; nf++) {
            f32x4 a = acc[nf];
            float s0 = pk(a[0], P),     s1 = pk(a[1], P - 1);
            float s2 = pk(a[2], P - 2), s3 = pk(a[3], P - 3);
            float h01 = fmaxf(s0, s1), l01 = fminf(s0, s1);
            float h23 = fmaxf(s2, s3), l23 = fminf(s2, s3);
            float m1 = fmaxf(h01, h23);                          // quad max
            float m2 = fmaxf(fminf(h01, h23), fmaxf(l01, l23));  // quad 2nd
            float n1 = fminf(t1[nf], m1); t1[nf] = fmaxf(t1[nf], m1);
            float n2 = fminf(t2[nf], n1); t2[nf] = fmaxf(t2[nf], n1);
            t3[nf] = fmaxf(t3[nf], n2);
            u1[nf] = fmaxf(u1[nf], m2);
        }
        P -= 16;
    }

    __syncthreads();  // all waves done streaming; reuse LDS for merge
    float* mrg = (float*)lds;  // [64 rows][130] (pad 2 -> 2-way banks only)
#pragma unroll
    for (int nf = 0; nf < 4; nf++) {
        int row = nf * 16 + col;
        int e = w * 16 + kq * 4;
        mrg[row * 130 + e + 0] = t1[nf];
        mrg[row * 130 + e + 1] = t2[nf];
        mrg[row * 130 + e + 2] = t3[nf];
        mrg[row * 130 + e + 3] = u1[nf];
    }
    __syncthreads();
    if (tid < 64) {
        float s1 = NEG, s2 = NEG, s3 = NEG, s4 = NEG;
#pragma unroll 8
        for (int e = 0; e < 128; e++) {
            float v = mrg[tid * 130 + e];
            float a1 = fminf(s1, v); s1 = fmaxf(s1, v);
            float a2 = fminf(s2, a1); s2 = fmaxf(s2, a1);
            float a3 = fminf(s3, a2); s3 = fmaxf(s3, a2);
            s4 = fmaxf(s4, a3);
        }
        long n = rbase + tid;
        cand[n * 4 + 0] = 8191 - (__float_as_int(s1) & 0x1FFF);
        cand[n * 4 + 1] = 8191 - (__float_as_int(s2) & 0x1FFF);
        cand[n * 4 + 2] = 8191 - (__float_as_int(s3) & 0x1FFF);
        cand[n * 4 + 3] = 8191 - (__float_as_int(s4) & 0x1FFF);
    }
}

// ---------------------------------------------------------------------------
// k4 v2: fp64 exact re-evaluation, thread-per-row (coalesced x reads).
// ---------------------------------------------------------------------------
__global__ void k_refine(const float* __restrict__ in, const float* __restrict__ cb,
                         const int* __restrict__ cand, int* __restrict__ idx_out,
                         float* __restrict__ idx_f) {
    int n = blockIdx.x * blockDim.x + threadIdx.x;
    if (n >= NROWS) return;
    int b = n >> 11, t = n & 2047;
    const float* xb = in + (long)b * DDIM * TT + t;
    int c[4];
#pragma unroll
    for (int k = 0; k < 4; k++) c[k] = cand[n * 4 + k];
    const float4* e0 = (const float4*)(cb + (long)c[0] * DDIM);
    const float4* e1 = (const float4*)(cb + (long)c[1] * DDIM);
    const float4* e2 = (const float4*)(cb + (long)c[2] * DDIM);
    const float4* e3 = (const float4*)(cb + (long)c[3] * DDIM);
    double dot[4] = {0, 0, 0, 0}, nrm[4] = {0, 0, 0, 0};
    for (int d4 = 0; d4 < 32; d4++) {
        float4 q0 = e0[d4], q1 = e1[d4], q2 = e2[d4], q3 = e3[d4];
#pragma unroll
        for (int j = 0; j < 4; j++) {
            double xd = (double)xb[(long)(d4 * 4 + j) * TT];
            double f0 = (double)((const float*)&q0)[j];
            double f1 = (double)((const float*)&q1)[j];
            double f2 = (double)((const float*)&q2)[j];
            double f3 = (double)((const float*)&q3)[j];
            dot[0] += xd * f0; nrm[0] += f0 * f0;
            dot[1] += xd * f1; nrm[1] += f1 * f1;
            dot[2] += xd * f2; nrm[2] += f2 * f2;
            dot[3] += xd * f3; nrm[3] += f3 * f3;
        }
    }
    double best = -1e300;
    int bi = 0x7fffffff;
#pragma unroll
    for (int k = 0; k < 4; k++) {
        double sv = dot[k] / fmax(sqrt(nrm[k]), 1e-12);
        if (sv > best || (sv == best && c[k] < bi)) { best = sv; bi = c[k]; }
    }
    idx_out[n] = bi;
    idx_f[n] = (float)bi;
}

// ---------------------------------------------------------------------------
// k5: out = x + (q - x) in [B,D,T] order + fp64 partial sums of (q-x)^2.
// ---------------------------------------------------------------------------
__global__ void k_out_loss(const float* __restrict__ in, const float* __restrict__ cb,
                           const int* __restrict__ idx, float* __restrict__ out,
                           double* __restrict__ part) {
    __shared__ double sd[256];
    double acc = 0.0;
    for (long e = (long)blockIdx.x * blockDim.x + threadIdx.x; e < ETOT;
         e += (long)gridDim.x * blockDim.x) {
        long t = e & 2047;
        long d = (e >> 11) & 127;
        long b = e >> 18;
        float xv = in[e];
        int n = (int)((b << 11) | t);
        float qv = cb[(long)idx[n] * DDIM + d];
        float diff = qv - xv;
        out[e] = xv + diff;
        acc += (double)diff * (double)diff;
    }
    sd[threadIdx.x] = acc;
    __syncthreads();
    for (int s = 128; s > 0; s >>= 1) {
        if (threadIdx.x < s) sd[threadIdx.x] += sd[threadIdx.x + s];
        __syncthreads();
    }
    if (threadIdx.x == 0) part[blockIdx.x] = sd[0];
}

__global__ void k_loss_final(const double* __restrict__ part, int np,
                             float* __restrict__ loss) {
    __shared__ double sd[256];
    double a = 0.0;
    for (int i = threadIdx.x; i < np; i += 256) a += part[i];
    sd[threadIdx.x] = a;
    __syncthreads();
    for (int s = 128; s > 0; s >>= 1) {
        if (threadIdx.x < s) sd[threadIdx.x] += sd[threadIdx.x + s];
        __syncthreads();
    }
    if (threadIdx.x == 0) {
        float m = (float)(sd[0] / (double)ETOT);
        loss[0] = m + 0.02f * m;
    }
}

// ---------------------------------------------------------------------------
extern "C" void kernel_launch(void* const* d_in, const int* in_sizes, int n_in,
                              void* d_out, int out_size, void* d_ws, size_t ws_size,
                              hipStream_t stream) {
    const float* inputs = (const float*)d_in[0];   // [16,128,2048] fp32
    const float* cb     = (const float*)d_in[1];   // [8192,128]    fp32
    float* outf = (float*)d_out;                   // [loss | out(B,D,T) | idx]

    char* ws = (char*)d_ws;
    _Float16* xh = (_Float16*)ws; ws += (long)NROWS * DDIM * 2;
    _Float16* eh = (_Float16*)ws; ws += (long)KCODES * DDIM * 2;
    int* cand    = (int*)ws;      ws += (long)NROWS * 4 * 4;
    int* idx     = (int*)ws;      ws += (long)NROWS * 4;
    double* part = (double*)ws;   ws += 2048 * 8;

    hipFuncSetAttribute((const void*)k_main,
                        hipFuncAttributeMaxDynamicSharedMemorySize, 65536);

    k_en_prep<<<dim3(2048), dim3(256), 0, stream>>>(cb, eh);
    k_x_prep<<<dim3(1024), dim3(256), 0, stream>>>(inputs, xh);
    k_main<<<dim3(512), dim3(512), 65536, stream>>>(xh, eh, cand);
    k_refine<<<dim3(128), dim3(256), 0, stream>>>(inputs, cb, cand, idx,
                                                  outf + 1 + (long)ETOT);
    k_out_loss<<<dim3(2048), dim3(256), 0, stream>>>(inputs, cb, idx, outf + 1, part);
    k_loss_final<<<dim3(1), dim3(256), 0, stream>>>(part, 2048, outf);
}

// Round 9
// 162.998 us; speedup vs baseline: 1.2844x; 1.0429x over previous
//
#include <hip/hip_runtime.h>
#include <hip/hip_bf16.h>

#define NROWS 32768
#define KCODES 8192
#define DDIM 128
#define TT 2048
#define ETOT 4194304  // 16*128*2048

typedef __attribute__((ext_vector_type(8))) _Float16 f16x8;
typedef __attribute__((ext_vector_type(4))) float f32x4;

// pack: (v & ~0x1FFF) | payload -- written to match v_bfi_b32 (1 VALU op).
// float compare then orders by (truncated value, then LOWER code first).
__device__ __forceinline__ float pk(float v, int payload) {
    return __int_as_float((__float_as_int(v) & 0xFFFFE000) | (payload & 0x1FFF));
}

__device__ __forceinline__ void async16(char* lds_uniform, const char* g_perlane) {
    __builtin_amdgcn_global_load_lds(
        (const __attribute__((address_space(1))) unsigned int*)g_perlane,
        (__attribute__((address_space(3))) unsigned int*)lds_uniform,
        16, 0, 0);
}

// ---------------------------------------------------------------------------
// k1: normalize codebook rows, fp32 -> fp16, store in MFMA A-fragment order
//     per 16-code tile (4KB each): k_main staging stays linear, reads clean.
// code w: tile16=w>>4, c=w&15 ; dim d: ks=d>>5, kq=(d>>3)&3, dr=d&7
// elem off = tile16*2048 + ks*512 + (kq*16 + c)*8 + dr
// ---------------------------------------------------------------------------
__global__ void k_en_prep(const float* __restrict__ cb,
                          _Float16* __restrict__ eh) {
    int w = (blockIdx.x * blockDim.x + threadIdx.x) >> 6;  // code id
    int l = threadIdx.x & 63;
    if (w >= KCODES) return;
    const float* row = cb + (long)w * DDIM;
    float v0 = row[l], v1 = row[l + 64];
    float ss = v0 * v0 + v1 * v1;
#pragma unroll
    for (int s = 1; s < 64; s <<= 1) ss += __shfl_xor(ss, s, 64);
    float inv = 1.0f / fmaxf(sqrtf(ss), 1e-12f);
    int tile = w >> 4, c = w & 15;
#pragma unroll
    for (int e = 0; e < 2; e++) {
        int d = l + e * 64;
        float v = (e ? v1 : v0) * inv;
        int ks = d >> 5, kq = (d >> 3) & 3, dr = d & 7;
        long off = (long)tile * 2048 + ks * 512 + (kq * 16 + c) * 8 + dr;
        eh[off] = (_Float16)v;
    }
}

// ---------------------------------------------------------------------------
// k2: transpose inputs [B,D,T] -> xh [N=B*T, D] row-major fp16.
// ---------------------------------------------------------------------------
__global__ void k_x_prep(const float* __restrict__ in,
                         _Float16* __restrict__ xh) {
    __shared__ float tb[64][65];
    int bid = blockIdx.x;
    int tt0 = (bid & 31) * 64;
    int dd0 = ((bid >> 5) & 1) * 64;
    int b = bid >> 6;
    const float* base = in + (long)b * DDIM * TT;
    int tl = threadIdx.x & 63;
    int dg = threadIdx.x >> 6;
#pragma unroll
    for (int i = 0; i < 16; i++) {
        int dd = dg + i * 4;
        tb[dd][tl] = base[(long)(dd0 + dd) * TT + tt0 + tl];
    }
    __syncthreads();
    int dl = threadIdx.x & 63;
    int tg = threadIdx.x >> 6;
#pragma unroll
    for (int i = 0; i < 16; i++) {
        int t = tg + i * 4;
        long n = (long)b * TT + tt0 + t;
        xh[n * DDIM + dd0 + dl] = (_Float16)tb[dl][t];
    }
}

// ---------------------------------------------------------------------------
// k3 v9: fp16 GEMM + packed selection, barrier-free private LDS streams,
// nf=8 (2x arithmetic intensity vs v8). 256 blocks x 512 thr; block = 128
// xrows; 8 waves each own a private 1024-code stream (64 tiles x 16 codes),
// double-buffered in an 8KB LDS slice via global_load_lds, counted vmcnt,
// NO main-loop barriers. Per tile: 4 async16 + 4 ds_read_b128 + 32 MFMA
// (setprio-wrapped) + 8-nf packed selection. bx[8][4]=128 VGPR stays
// resident under __launch_bounds__(512,2) (256-VGPR budget; r6 lesson).
// ---------------------------------------------------------------------------
__global__ __launch_bounds__(512, 2) void k_main(const _Float16* __restrict__ xh,
                                                 const _Float16* __restrict__ eh,
                                                 int* __restrict__ cand) {
    extern __shared__ char lds[];
    const int tid = threadIdx.x;
    const int l = tid & 63;
    const int w = tid >> 6;          // 0..7 : wave id, owns codes [w*1024, w*1024+1024)
    const int col = l & 15, kq = l >> 4;
    const long rbase = (long)blockIdx.x * 128;

    // B-operand x-fragments, loaded once: 8 nf x 4 ks = 128 VGPR
    f16x8 bx[8][4];
#pragma unroll
    for (int nf = 0; nf < 8; nf++) {
        long n = rbase + nf * 16 + col;
#pragma unroll
        for (int ks = 0; ks < 4; ks++)
            bx[nf][ks] = *(const f16x8*)(xh + n * DDIM + ks * 32 + kq * 8);
    }

    const float NEG = __int_as_float(0xFF800000);  // -inf (payload bits 0)
    float t1[8], t2[8], t3[8], u1[8];
#pragma unroll
    for (int i = 0; i < 8; i++) { t1[i] = t2[i] = t3[i] = u1[i] = NEG; }

    int P = 8191 - (w * 1024 + kq * 4);  // payload; code = 8191 - payload

    const char* gsrc = (const char*)eh + (long)w * 64 * 4096 + l * 16;
    char* lbase = lds + w * 8192;        // private 2 x 4KB double buffer

    // prologue: stage tile 0 into buf 0
#pragma unroll
    for (int ks = 0; ks < 4; ks++)
        async16(lbase + ks * 1024, gsrc + ks * 1024);

    for (int t = 0; t < 64; ++t) {
        if (t < 63) {
            const char* gs = gsrc + (t + 1) * 4096;
            char* nb = lbase + ((t + 1) & 1) * 4096;
#pragma unroll
            for (int ks = 0; ks < 4; ks++)
                async16(nb + ks * 1024, gs + ks * 1024);
            asm volatile("s_waitcnt vmcnt(4)" ::: "memory");  // tile t landed
        } else {
            asm volatile("s_waitcnt vmcnt(0)" ::: "memory");  // final drain
        }

        const char* buf = lbase + (t & 1) * 4096;
        f16x8 ah[4];
#pragma unroll
        for (int ks = 0; ks < 4; ks++)
            ah[ks] = *(const f16x8*)(buf + ks * 1024 + l * 16);

        f32x4 acc[8];
#pragma unroll
        for (int nf = 0; nf < 8; nf++) acc[nf] = (f32x4){0.f, 0.f, 0.f, 0.f};
        __builtin_amdgcn_s_setprio(1);
#pragma unroll
        for (int nf = 0; nf < 8; nf++) {
            acc[nf] = __builtin_amdgcn_mfma_f32_16x16x32_f16(ah[0], bx[nf][0], acc[nf], 0, 0, 0);
            acc[nf] = __builtin_amdgcn_mfma_f32_16x16x32_f16(ah[1], bx[nf][1], acc[nf], 0, 0, 0);
            acc[nf] = __builtin_amdgcn_mfma_f32_16x16x32_f16(ah[2], bx[nf][2], acc[nf], 0, 0, 0);
            acc[nf] = __builtin_amdgcn_mfma_f32_16x16x32_f16(ah[3], bx[nf][3], acc[nf], 0, 0, 0);
        }
        __builtin_amdgcn_s_setprio(0);

        // index-free selection on packed floats (code = w*1024 + t*16 + kq*4 + j)
#pragma unroll
        for (int nf = 0; nf < 8; nf++) {
            f32x4 a = acc[nf];
            float s0 = pk(a[0], P),     s1 = pk(a[1], P - 1);
            float s2 = pk(a[2], P - 2), s3 = pk(a[3], P - 3);
            float h01 = fmaxf(s0, s1), l01 = fminf(s0, s1);
            float h23 = fmaxf(s2, s3), l23 = fminf(s2, s3);
            float m1 = fmaxf(h01, h23);                          // quad max
            float m2 = fmaxf(fminf(h01, h23), fmaxf(l01, l23));  // quad 2nd
            float n1 = fminf(t1[nf], m1); t1[nf] = fmaxf(t1[nf], m1);
            float n2 = fminf(t2[nf], n1); t2[nf] = fmaxf(t2[nf], n1);
            t3[nf] = fmaxf(t3[nf], n2);
            u1[nf] = fmaxf(u1[nf], m2);
        }
        P -= 16;
    }

    __syncthreads();  // all waves done streaming; reuse LDS for merge
    float* mrg = (float*)lds;  // [128 rows][130]
#pragma unroll
    for (int nf = 0; nf < 8; nf++) {
        int row = nf * 16 + col;
        int e = w * 16 + kq * 4;
        mrg[row * 130 + e + 0] = t1[nf];
        mrg[row * 130 + e + 1] = t2[nf];
        mrg[row * 130 + e + 2] = t3[nf];
        mrg[row * 130 + e + 3] = u1[nf];
    }
    __syncthreads();
    if (tid < 128) {
        float s1 = NEG, s2 = NEG, s3 = NEG, s4 = NEG;
#pragma unroll 8
        for (int e = 0; e < 128; e++) {
            float v = mrg[tid * 130 + e];
            float a1 = fminf(s1, v); s1 = fmaxf(s1, v);
            float a2 = fminf(s2, a1); s2 = fmaxf(s2, a1);
            float a3 = fminf(s3, a2); s3 = fmaxf(s3, a2);
            s4 = fmaxf(s4, a3);
        }
        long n = rbase + tid;
        cand[n * 4 + 0] = 8191 - (__float_as_int(s1) & 0x1FFF);
        cand[n * 4 + 1] = 8191 - (__float_as_int(s2) & 0x1FFF);
        cand[n * 4 + 2] = 8191 - (__float_as_int(s3) & 0x1FFF);
        cand[n * 4 + 3] = 8191 - (__float_as_int(s4) & 0x1FFF);
    }
}

// ---------------------------------------------------------------------------
// k4 v2: fp64 exact re-evaluation, thread-per-row (coalesced x reads).
// ---------------------------------------------------------------------------
__global__ void k_refine(const float* __restrict__ in, const float* __restrict__ cb,
                         const int* __restrict__ cand, int* __restrict__ idx_out,
                         float* __restrict__ idx_f) {
    int n = blockIdx.x * blockDim.x + threadIdx.x;
    if (n >= NROWS) return;
    int b = n >> 11, t = n & 2047;
    const float* xb = in + (long)b * DDIM * TT + t;
    int c[4];
#pragma unroll
    for (int k = 0; k < 4; k++) c[k] = cand[n * 4 + k];
    const float4* e0 = (const float4*)(cb + (long)c[0] * DDIM);
    const float4* e1 = (const float4*)(cb + (long)c[1] * DDIM);
    const float4* e2 = (const float4*)(cb + (long)c[2] * DDIM);
    const float4* e3 = (const float4*)(cb + (long)c[3] * DDIM);
    double dot[4] = {0, 0, 0, 0}, nrm[4] = {0, 0, 0, 0};
    for (int d4 = 0; d4 < 32; d4++) {
        float4 q0 = e0[d4], q1 = e1[d4], q2 = e2[d4], q3 = e3[d4];
#pragma unroll
        for (int j = 0; j < 4; j++) {
            double xd = (double)xb[(long)(d4 * 4 + j) * TT];
            double f0 = (double)((const float*)&q0)[j];
            double f1 = (double)((const float*)&q1)[j];
            double f2 = (double)((const float*)&q2)[j];
            double f3 = (double)((const float*)&q3)[j];
            dot[0] += xd * f0; nrm[0] += f0 * f0;
            dot[1] += xd * f1; nrm[1] += f1 * f1;
            dot[2] += xd * f2; nrm[2] += f2 * f2;
            dot[3] += xd * f3; nrm[3] += f3 * f3;
        }
    }
    double best = -1e300;
    int bi = 0x7fffffff;
#pragma unroll
    for (int k = 0; k < 4; k++) {
        double sv = dot[k] / fmax(sqrt(nrm[k]), 1e-12);
        if (sv > best || (sv == best && c[k] < bi)) { best = sv; bi = c[k]; }
    }
    idx_out[n] = bi;
    idx_f[n] = (float)bi;
}

// ---------------------------------------------------------------------------
// k5: out = x + (q - x) in [B,D,T] order + fp64 partial sums of (q-x)^2.
// ---------------------------------------------------------------------------
__global__ void k_out_loss(const float* __restrict__ in, const float* __restrict__ cb,
                           const int* __restrict__ idx, float* __restrict__ out,
                           double* __restrict__ part) {
    __shared__ double sd[256];
    double acc = 0.0;
    for (long e = (long)blockIdx.x * blockDim.x + threadIdx.x; e < ETOT;
         e += (long)gridDim.x * blockDim.x) {
        long t = e & 2047;
        long d = (e >> 11) & 127;
        long b = e >> 18;
        float xv = in[e];
        int n = (int)((b << 11) | t);
        float qv = cb[(long)idx[n] * DDIM + d];
        float diff = qv - xv;
        out[e] = xv + diff;
        acc += (double)diff * (double)diff;
    }
    sd[threadIdx.x] = acc;
    __syncthreads();
    for (int s = 128; s > 0; s >>= 1) {
        if (threadIdx.x < s) sd[threadIdx.x] += sd[threadIdx.x + s];
        __syncthreads();
    }
    if (threadIdx.x == 0) part[blockIdx.x] = sd[0];
}

__global__ void k_loss_final(const double* __restrict__ part, int np,
                             float* __restrict__ loss) {
    __shared__ double sd[256];
    double a = 0.0;
    for (int i = threadIdx.x; i < np; i += 256) a += part[i];
    sd[threadIdx.x] = a;
    __syncthreads();
    for (int s = 128; s > 0; s >>= 1) {
        if (threadIdx.x < s) sd[threadIdx.x] += sd[threadIdx.x + s];
        __syncthreads();
    }
    if (threadIdx.x == 0) {
        float m = (float)(sd[0] / (double)ETOT);
        loss[0] = m + 0.02f * m;
    }
}

// ---------------------------------------------------------------------------
extern "C" void kernel_launch(void* const* d_in, const int* in_sizes, int n_in,
                              void* d_out, int out_size, void* d_ws, size_t ws_size,
                              hipStream_t stream) {
    const float* inputs = (const float*)d_in[0];   // [16,128,2048] fp32
    const float* cb     = (const float*)d_in[1];   // [8192,128]    fp32
    float* outf = (float*)d_out;                   // [loss | out(B,D,T) | idx]

    char* ws = (char*)d_ws;
    _Float16* xh = (_Float16*)ws; ws += (long)NROWS * DDIM * 2;
    _Float16* eh = (_Float16*)ws; ws += (long)KCODES * DDIM * 2;
    int* cand    = (int*)ws;      ws += (long)NROWS * 4 * 4;
    int* idx     = (int*)ws;      ws += (long)NROWS * 4;
    double* part = (double*)ws;   ws += 2048 * 8;

    // main loop: 8 waves x 8KB private dbuf = 64KB; merge: 128*130*4 = 66560
    hipFuncSetAttribute((const void*)k_main,
                        hipFuncAttributeMaxDynamicSharedMemorySize, 66560);

    k_en_prep<<<dim3(2048), dim3(256), 0, stream>>>(cb, eh);
    k_x_prep<<<dim3(1024), dim3(256), 0, stream>>>(inputs, xh);
    k_main<<<dim3(256), dim3(512), 66560, stream>>>(xh, eh, cand);
    k_refine<<<dim3(128), dim3(256), 0, stream>>>(inputs, cb, cand, idx,
                                                  outf + 1 + (long)ETOT);
    k_out_loss<<<dim3(2048), dim3(256), 0, stream>>>(inputs, cb, idx, outf + 1, part);
    k_loss_final<<<dim3(1), dim3(256), 0, stream>>>(part, 2048, outf);
}